// Round 14
// baseline (168.763 us; speedup 1.0000x reference)
//
#include <hip/hip_runtime.h>
#include <hip/hip_fp16.h>

// CapsuleLayer dynamic routing — round 18: register-resident W + batch-phased
// softmax. r16/r17 post-mortem: the LDS-staged-W architecture has a hard
// DS-pipe floor (~755K ds_read_b128/round; b-sharing can't reduce the
// instruction count because broadcast halves unique-bytes/instr) -> rounds
// pinned ~30-35us. This round returns to the baseline's W-in-registers
// mapping (wave = (Gp,j), 8xint4 = 32 VGPR fragment, amortized over BT=8
// batch elements -> W read from L2 once per 8 b) but removes the baseline's
// two serializers: softmax is BATCH-PHASED (ph1: logits for all 8 b -> one
// barrier -> Z table -> one barrier -> ph3: weighted sums; 3 barriers/kernel
// vs 16) and s goes via per-wave plain stores + reduce kernel (no atomics).
// hat is recomputed in ph3 (32 fdot2, VALU-cheap) instead of stored; the ph3
// X-pointer is laundered (asm on the 32-bit LDS pointer) so CSE cannot keep
// 8 b's worth of hat live across the barriers (the r11 spill pattern).

#define IC 1152
#define IE 8
#define NC 10
#define DV 16
#define NB 256
#define NW (IC * NC * IE * DV)  // 1,474,560
#define SOUT (NC * DV)          // 160
#define GPB (IC / 32)           // 36
#define BT 8                    // batch elements per block
#define NBG (NB / BT)           // 32
#define TPB (NC * 64)           // 640: wave w <-> output capsule j

typedef _Float16 h2 __attribute__((ext_vector_type(2)));
union WChunk { int4 v; h2 p[4]; _Float16 h[8]; };
union XFrag { int4 v; h2 p[4]; };

#if defined(__has_builtin) && __has_builtin(__builtin_amdgcn_fdot2)
__device__ inline float fdot2(h2 a, h2 b, float c) {
    return __builtin_amdgcn_fdot2(a, b, c, false);
}
#else
__device__ inline float fdot2(h2 a, h2 b, float c) {
    return fmaf((float)a.x, (float)b.x, fmaf((float)a.y, (float)b.y, c));
}
#endif

// W fp32 [i][j][e][d] -> fp16 chunks Wc[((Gp*10+j)*8+k)*64 + lane], where
// lane = h*32+r, i = Gp*32+r, d = h*8+k; chunk holds e=0..7 halves of W[i,j,:,d].
__global__ void wprep_kernel(const float* __restrict__ W, int4* __restrict__ Wc) {
    const int t = blockIdx.x * blockDim.x + threadIdx.x;
    if (t >= NW / 8) return;
    const int lane = t & 63;
    const int h = lane >> 5, r = lane & 31;
    const int k = (t >> 6) & 7;
    const int r2 = t >> 9;  // Gp*10 + j
    const int j = r2 % NC, Gp = r2 / NC;
    const int i = Gp * 32 + r;
    const int d = h * 8 + k;
    const float* src = W + ((size_t)(i * NC + j) * IE) * DV + d;  // e-stride DV
    WChunk c;
#pragma unroll
    for (int e = 0; e < IE; ++e) c.h[e] = (_Float16)src[(size_t)e * DV];
    Wc[t] = c.v;
}

// Splitting butterfly over the 32 r-lanes of one d-half: s8[8] -> one value
// per 4-lane group; lanes (r&3)==0 store to dst8[dl].
__device__ inline void butterfly_store(const float* s8, int r, float* dst8) {
    float t4[4];
#pragma unroll
    for (int d = 0; d < 4; ++d) {
        const bool hi = (r & 16);
        const float mine = hi ? s8[d + 4] : s8[d];
        const float send = hi ? s8[d] : s8[d + 4];
        t4[d] = mine + __shfl_xor(send, 16);
    }
    float t2[2];
#pragma unroll
    for (int d = 0; d < 2; ++d) {
        const bool hi = (r & 8);
        const float mine = hi ? t4[d + 2] : t4[d];
        const float send = hi ? t4[d] : t4[d + 2];
        t2[d] = mine + __shfl_xor(send, 8);
    }
    float t1;
    {
        const bool hi = (r & 4);
        const float mine = hi ? t2[1] : t2[0];
        const float send = hi ? t2[0] : t2[1];
        t1 = mine + __shfl_xor(send, 4);
    }
    t1 += __shfl_xor(t1, 2);
    t1 += __shfl_xor(t1, 1);
    if ((r & 3) == 0) {
        const int dl = (r >> 2) & 7;  // bit map: r4->d2, r3->d1, r2->d0
        dst8[dl] = t1;
    }
}

// One routing round. Block = (Gp, group of 8 b); wave w = output capsule j;
// lane g = h*32+r covers row i=Gp*32+r, d-half h. W fragment (8 int4) lives
// in registers for the whole kernel (read from L2 once per 8 b).
// RD=0: c = softmax(bias) (b-independent, computed once via LDS tables).
// RD>0: ph1 logits for all 8 b -> barrier -> Z -> barrier -> ph3 sums.
template <int RD>
__global__ __launch_bounds__(TPB) void round_caps(
    const float* __restrict__ X,     // [B, IC, IE] fp32
    const int4* __restrict__ Wc,     // coalesced fp16 W (see wprep)
    const float* __restrict__ bias,  // [IC*NC] fp32
    const float* __restrict__ vF,    // [B*160] f32 (RD>0)
    float* __restrict__ sp)          // [GPB*NB*SOUT] partial s
{
    __shared__ __align__(16) int4 Xs[BT * 32];  // packed-h2 X rows (4 KB)
    __shared__ float lg[BT * 32 * 11];          // exp(logit), stride 11 (11.3 KB)
    __shared__ float rZ[BT * 32];               // 1/Z per (bi, row)

    const int Gp = blockIdx.x;  // 0..35
    const int bg = blockIdx.y;  // 0..31
    const int tid = threadIdx.x;
    const int j = tid >> 6;  // wave = output capsule
    const int g = tid & 63;
    const int h = g >> 5;    // d-half: d = h*8 + k
    const int r = g & 31;    // row within group
    const int i = Gp * 32 + r;

    // ---- W fragment -> registers (8 int4 = 32 VGPR, coalesced) ----
    WChunk wreg[8];
    {
        const int4* wp = Wc + ((size_t)(Gp * NC + j) * 8) * 64 + g;
#pragma unroll
        for (int k = 0; k < 8; ++k) wreg[k].v = wp[k * 64];
    }
    const float bj = bias[i * NC + j];

    // ---- stage X rows for the 8 b's, packed to h2 (256 int4) ----
    for (int t = tid; t < BT * 32; t += TPB) {
        const int bi = t >> 5, rr = t & 31;
        const float4* xr =
            (const float4*)(X + ((size_t)(bg * BT + bi) * IC + Gp * 32 + rr) * IE);
        const float4 x0 = xr[0], x1 = xr[1];
        XFrag xf;
        xf.p[0] = h2{(_Float16)x0.x, (_Float16)x0.y};
        xf.p[1] = h2{(_Float16)x0.z, (_Float16)x0.w};
        xf.p[2] = h2{(_Float16)x1.x, (_Float16)x1.y};
        xf.p[3] = h2{(_Float16)x1.z, (_Float16)x1.w};
        Xs[t] = xf.v;
    }

    float c0 = 0.f;
    if constexpr (RD == 0) {
        // b-independent softmax(bias): table once, no per-b work
        if (h == 0) lg[r * 11 + j] = __expf(bj);
        __syncthreads();  // also covers Xs
        for (int t = tid; t < 32; t += TPB) {
            float Z = 0.f;
#pragma unroll
            for (int jj = 0; jj < NC; ++jj) Z += lg[t * 11 + jj];
            rZ[t] = 1.f / Z;
        }
        __syncthreads();
        c0 = lg[r * 11 + j] * rZ[r];
    } else {
        __syncthreads();  // Xs ready

        // ---- ph1: logits for all 8 b (no per-b barriers) ----
#pragma unroll 2
        for (int bi = 0; bi < BT; ++bi) {
            const int b = bg * BT + bi;
            XFrag xu;
            xu.v = Xs[bi * 32 + r];
            float hat[8];
#pragma unroll
            for (int k = 0; k < 8; ++k) {
                float a = 0.f;
#pragma unroll
                for (int q = 0; q < 4; ++q) a = fdot2(xu.p[q], wreg[k].p[q], a);
                hat[k] = a;
            }
            const float4* vp = (const float4*)(vF + (size_t)b * SOUT + j * DV + h * 8);
            const float4 va = vp[0], vb = vp[1];
            const float ah = hat[0] * va.x + hat[1] * va.y + hat[2] * va.z +
                             hat[3] * va.w + hat[4] * vb.x + hat[5] * vb.y +
                             hat[6] * vb.z + hat[7] * vb.w;
            const float lt = bj + ah + __shfl_xor(ah, 32);
            if (h == 0) lg[(bi * 32 + r) * 11 + j] = __expf(lt);
        }
        __syncthreads();

        // ---- ph2: 1/Z for the 256 (bi,row) pairs ----
        for (int t = tid; t < BT * 32; t += TPB) {
            float Z = 0.f;
#pragma unroll
            for (int jj = 0; jj < NC; ++jj) Z += lg[t * 11 + jj];
            rZ[t] = 1.f / Z;
        }
        __syncthreads();
    }

    // ---- ph3: weighted sums (hat recomputed from register W) ----
    // Launder the LDS X pointer so ph1's hat values cannot be CSE'd across
    // the barriers into 8-b-wide residency (the r11 spill pattern).
    const int4* xsp = Xs;
    asm volatile("" : "+v"(xsp));
#pragma unroll 2
    for (int bi = 0; bi < BT; ++bi) {
        const int b = bg * BT + bi;
        XFrag xu;
        xu.v = xsp[bi * 32 + r];
        float cv;
        if constexpr (RD == 0) {
            cv = c0;
        } else {
            cv = lg[(bi * 32 + r) * 11 + j] * rZ[bi * 32 + r];
        }
        float s8[8];
#pragma unroll
        for (int k = 0; k < 8; ++k) {
            float a = 0.f;
#pragma unroll
            for (int q = 0; q < 4; ++q) a = fdot2(xu.p[q], wreg[k].p[q], a);
            s8[k] = cv * a;
        }
        butterfly_store(s8, r, sp + ((size_t)Gp * NB + b) * SOUT + j * DV + h * 8);
    }
}

// Per-round reduce: v = squash(sum over 36 Gp partials) (+ vprev for P2).
template <int P>
__global__ __launch_bounds__(192) void reduce_caps(
    const float* __restrict__ sp, const float* __restrict__ vprevF,
    float* __restrict__ voutF, float* __restrict__ out) {
    const int b = blockIdx.x, t = threadIdx.x;
    if (t >= SOUT) return;
    float sv = 0.f;
#pragma unroll
    for (int gq = 0; gq < GPB; ++gq) sv += sp[((size_t)gq * NB + b) * SOUT + t];
    float s2 = sv * sv;
#pragma unroll
    for (int mk = 8; mk >= 1; mk >>= 1) s2 += __shfl_xor(s2, mk, 16);
    float vv = sqrtf(s2) / (1.f + s2) * sv;
    if constexpr (P == 2) vv += vprevF[(size_t)b * SOUT + t];  // vsum = v1+v2
    if constexpr (P == 3) out[(size_t)b * SOUT + t] = vv;
    else voutF[(size_t)b * SOUT + t] = vv;
}

extern "C" void kernel_launch(void* const* d_in, const int* in_sizes, int n_in,
                              void* d_out, int out_size, void* d_ws, size_t ws_size,
                              hipStream_t stream) {
    const float* X = (const float*)d_in[0];     // [256,1152,8]
    const float* W = (const float*)d_in[1];     // [1152,10,8,16]
    const float* bias = (const float*)d_in[2];  // [1,1152,10]
    float* out = (float*)d_out;

    // ws: Wc 2.95MB | sp 5.9MB (reused each round) | v1F 160KB | vsF 160KB
    int4* Wc = (int4*)d_ws;
    float* sp = (float*)(Wc + NW / 8);
    float* v1F = sp + (size_t)GPB * NB * SOUT;
    float* vsF = v1F + (size_t)NB * SOUT;

    wprep_kernel<<<dim3(720), dim3(256), 0, stream>>>(W, Wc);

    dim3 rg(GPB, NBG);  // (36, 32)
    round_caps<0><<<rg, TPB, 0, stream>>>(X, Wc, bias, nullptr, sp);
    reduce_caps<1><<<dim3(NB), dim3(192), 0, stream>>>(sp, nullptr, v1F, nullptr);
    round_caps<1><<<rg, TPB, 0, stream>>>(X, Wc, bias, v1F, sp);
    reduce_caps<2><<<dim3(NB), dim3(192), 0, stream>>>(sp, v1F, vsF, nullptr);
    round_caps<2><<<rg, TPB, 0, stream>>>(X, Wc, bias, vsF, sp);
    reduce_caps<3><<<dim3(NB), dim3(192), 0, stream>>>(sp, nullptr, nullptr, out);
}